// Round 2
// baseline (1473.881 us; speedup 1.0000x reference)
//
#include <hip/hip_runtime.h>
#include <stdint.h>

#define NUM_CAMS 12
#define NUM_JOINTS 23
#define RB 32                 // record bytes: 23 u8 joints + pad, 32B aligned
#define RW 8                  // record dwords
#define G 104
#define HALF 52
#define L 160
#define HM_W 512
#define HM_H 512
#define HW (HM_W * HM_H)      // 262144
#define G3 (G * G * G)        // 1124864
#define OFFSET (-160.0f)
#define SPACING 2.0f
#define CHUNKS (G3 / 256)     // 4394 voxel-chunks of 256
#define CHUNKS_PAD 4400       // rounded up to multiple of 8 (XCD count)

// Kernel 1: heatmaps [B*C, J, HW] f32 -> trans [B*C, HW, RB] u8.
// 1 hw per thread: 23 scalar loads (256B/wave/instr, coalesced).
// LDS transpose -> block writes its 8KB output region as fully-coalesced
// 1KB/instr uint4 stores (old version scattered 16B per 64B line, 4x
// transaction inflation on the 201MB write stream).
__global__ __launch_bounds__(256) void quant_transpose_kernel(
    const float* __restrict__ heat, uint4* __restrict__ trans)
{
    __shared__ uint32_t lds[RW][257];   // stride 257: 2-way banks (free) both dirs
    const int t = threadIdx.x;
    const int hw = blockIdx.x * 256 + t;
    const int bc = blockIdx.y;
    const float* src = heat + (size_t)bc * NUM_JOINTS * HW + hw;

    uint32_t pk[RW];
#pragma unroll
    for (int k = 0; k < RW; k++) pk[k] = 0u;

#pragma unroll
    for (int j = 0; j < NUM_JOINTS; j++) {
        const float v = src[(size_t)j * HW];
        const uint32_t q = (uint32_t)fmaf(v, 255.0f, 0.5f);
        pk[j >> 2] |= q << ((j & 3) * 8);
    }

#pragma unroll
    for (int k = 0; k < RW; k++) lds[k][t] = pk[k];   // banks t&31: conflict-free
    __syncthreads();

    // block output region: 256 records * 32B = 8KB = 512 uint4, lane-contiguous
    uint4* dst = trans + ((size_t)bc * HW + (size_t)blockIdx.x * 256) * 2;
#pragma unroll
    for (int half = 0; half < 2; half++) {
        const int i = half * 256 + t;       // uint4 index within block region
        const int r = i >> 1;               // record
        const int h = (i & 1) * 4;          // which half of the record
        dst[i] = make_uint4(lds[h + 0][r], lds[h + 1][r],
                            lds[h + 2][r], lds[h + 3][r]);
    }
}

// Kernel 2: per (b, voxel): 12 lookup int2 loads + 12 record loads (24B each),
// SWAR u8->u16x2 accumulation. Changes vs 1449us baseline:
//  - launch_bounds(256,8): occupancy 72% -> ~100% (36 VGPR, not reg-limited),
//    more outstanding random misses.
//  - batch b folded into blockIdx.x with 8-stride pairing: the two batches'
//    overlapping reproLookup windows (~55% volume) are read by blocks on the
//    SAME XCD at the SAME time -> batch-1 lookup reads become L2 hits.
__global__ __launch_bounds__(256, 8) void gather_kernel(
    const uint8_t* __restrict__ trans, const float* __restrict__ center,
    const int* __restrict__ lookup, float* __restrict__ out, int nbatch)
{
    // swizzle: groups of 8*nbatch blocks = 8 chunks x nbatch batches.
    // chunk (g*8 + k, b=0) and (g*8 + k, b=1) are exactly 8 apart in dispatch
    // order -> same XCD under round-robin.
    const int per = 8 * nbatch;
    const int g = blockIdx.x / per;
    const int r = blockIdx.x % per;
    const int b = r >> 3;
    const int chunk = g * 8 + (r & 7);
    if (chunk >= CHUNKS) return;

    const int vox = chunk * 256 + threadIdx.x;   // z fastest

    const int z = vox % G;
    const int t = vox / G;
    const int y = t % G;
    const int x = t / G;

    int s0 = (int)((center[b * 3 + 0] - OFFSET) / SPACING) - HALF;
    int s1 = (int)((center[b * 3 + 1] - OFFSET) / SPACING) - HALF;
    int s2 = (int)((center[b * 3 + 2] - OFFSET) / SPACING) - HALF;
    s0 = min(max(s0, 0), L - G);
    s1 = min(max(s1, 0), L - G);
    s2 = min(max(s2, 0), L - G);

    const int xi = s0 + x, yi = s1 + y, zi = s2 + z;
    const size_t lbase = (((size_t)xi * L + yi) * L + zi) * 2;

    // phase 1: all lookup loads in flight
    int2 uv[NUM_CAMS];
#pragma unroll
    for (int c = 0; c < NUM_CAMS; c++)
        uv[c] = *(const int2*)(lookup + (size_t)c * (L * L * L * 2) + lbase);

    // phase 2: all record loads in flight (24B = dwordx4 + dwordx2 each)
    const uint8_t* tb = trans + (size_t)b * NUM_CAMS * HW * RB;
    uint4 qa[NUM_CAMS];
    uint2 qb[NUM_CAMS];
#pragma unroll
    for (int c = 0; c < NUM_CAMS; c++) {
        const int flat = uv[c].y * HM_W + uv[c].x;
        const uint8_t* p = tb + ((size_t)c * HW + (size_t)flat) * RB;
        qa[c] = *(const uint4*)p;
        qb[c] = *(const uint2*)(p + 16);
    }

    // phase 3: SWAR accumulate — two u8 values per u16 lane, 12*255 < 65536
    uint32_t accLo[6] = {0, 0, 0, 0, 0, 0};
    uint32_t accHi[6] = {0, 0, 0, 0, 0, 0};
#pragma unroll
    for (int c = 0; c < NUM_CAMS; c++) {
        const uint32_t d[6] = {qa[c].x, qa[c].y, qa[c].z, qa[c].w,
                               qb[c].x, qb[c].y};
#pragma unroll
        for (int k = 0; k < 6; k++) {
            accLo[k] += d[k] & 0x00ff00ffu;          // joints 4k, 4k+2
            accHi[k] += (d[k] >> 8) & 0x00ff00ffu;   // joints 4k+1, 4k+3
        }
    }

    const float scale = 1.0f / (255.0f * (float)NUM_CAMS);
    float* o = out + (size_t)b * NUM_JOINTS * G3 + vox;
#pragma unroll
    for (int k = 0; k < 6; k++) {
        const int j = 4 * k;
        o[(size_t)j * G3]       = (float)(accLo[k] & 0xffffu) * scale;
        o[(size_t)(j + 1) * G3] = (float)(accHi[k] & 0xffffu) * scale;
        o[(size_t)(j + 2) * G3] = (float)(accLo[k] >> 16) * scale;
        if (j + 3 < NUM_JOINTS)
            o[(size_t)(j + 3) * G3] = (float)(accHi[k] >> 16) * scale;
    }
}

// Fallback (ws too small): direct fp32 gather from native layout.
__global__ __launch_bounds__(256) void gather_direct_kernel(
    const float* __restrict__ heat, const float* __restrict__ center,
    const int* __restrict__ lookup, float* __restrict__ out)
{
    const int vox = blockIdx.x * 256 + threadIdx.x;
    const int b = blockIdx.y;

    const int z = vox % G;
    const int t = vox / G;
    const int y = t % G;
    const int x = t / G;

    int s0 = (int)((center[b * 3 + 0] - OFFSET) / SPACING) - HALF;
    int s1 = (int)((center[b * 3 + 1] - OFFSET) / SPACING) - HALF;
    int s2 = (int)((center[b * 3 + 2] - OFFSET) / SPACING) - HALF;
    s0 = min(max(s0, 0), L - G);
    s1 = min(max(s1, 0), L - G);
    s2 = min(max(s2, 0), L - G);

    const int xi = s0 + x, yi = s1 + y, zi = s2 + z;

    float acc[NUM_JOINTS];
#pragma unroll
    for (int j = 0; j < NUM_JOINTS; j++) acc[j] = 0.0f;

    for (int c = 0; c < NUM_CAMS; c++) {
        const size_t lidx = ((((size_t)c * L + xi) * L + yi) * L + zi) * 2;
        const int2 uvc = *(const int2*)(lookup + lidx);
        const int flat = uvc.y * HM_W + uvc.x;
        const float* hp = heat + (((size_t)b * NUM_CAMS + c) * NUM_JOINTS) * HW
                               + (size_t)flat;
#pragma unroll
        for (int j = 0; j < NUM_JOINTS; j++)
            acc[j] += hp[(size_t)j * HW];
    }

    const float scale = 1.0f / (float)NUM_CAMS;
    float* o = out + (size_t)b * NUM_JOINTS * G3 + vox;
#pragma unroll
    for (int j = 0; j < NUM_JOINTS; j++)
        o[(size_t)j * G3] = acc[j] * scale;
}

extern "C" void kernel_launch(void* const* d_in, const int* in_sizes, int n_in,
                              void* d_out, int out_size, void* d_ws, size_t ws_size,
                              hipStream_t stream)
{
    const float* heat   = (const float*)d_in[0];
    const float* center = (const float*)d_in[1];
    const int*   lookup = (const int*)d_in[2];
    float* out = (float*)d_out;

    const int B = in_sizes[1] / 3;   // = 2
    const size_t need = (size_t)B * NUM_CAMS * HW * RB;   // ~201 MB

    if (ws_size >= need) {
        uint32_t* trans = (uint32_t*)d_ws;
        dim3 g1(HW / 256, B * NUM_CAMS);            // 1024 x 24
        quant_transpose_kernel<<<g1, 256, 0, stream>>>(heat, (uint4*)trans);
        dim3 g2(CHUNKS_PAD * B, 1);                 // 8800 blocks, b folded in
        gather_kernel<<<g2, 256, 0, stream>>>((const uint8_t*)trans, center,
                                              lookup, out, B);
    } else {
        dim3 g2(G3 / 256, B);
        gather_direct_kernel<<<g2, 256, 0, stream>>>(heat, center, lookup, out);
    }
}